// Round 6
// baseline (514.978 us; speedup 1.0000x reference)
//
#include <hip/hip_runtime.h>

// proto-contrastive CE loss via bf16 MFMA, persistent waves + register prefetch.
// features [N=1e6, D=128] f32, labels [N] i32, prototypes [C=150, D=128] f32.
// out[0] = mean_n( logsumexp_c(f_hat·p_c/T) - f_hat·p_lbl/T )
//
// R6: launch_bounds(256,4) gave a 128-reg/wave budget; allocator split it
// 64 VGPR + 64 AGPR and spilled ~100 VGPRs of live state (160 MB scratch
// writes, 1.4 GB fetch, 2 rounds identical). (256,3) -> ~170-reg budget,
// live set ~150 (buf 32 + bfrag 8 + acc 40 AGPR + temps) fits. 12 waves/CU
// still covers HBM latency (12 x 8 KB in flight >> 11 KB needed).

#define NS 1000000
#define NC 150
#define NCP 160              // classes padded to 10 tiles of 16
#define FD 128
#define NTILE (NS / 16)      // 62500 16-sample tiles
#define NBLK 1024            // grid-stride persistent blocks
#define NWAVE (NBLK * 4)

static constexpr float INV_T  = 1.0f / 0.15f;
static constexpr float MB     = 1.0f / 0.15f;     // fixed LSE shift, |logit| <= 1/T
static constexpr float LOG2E  = 1.4426950408889634f;
static constexpr float B2     = -MB * LOG2E;      // exp(x-MB) = exp2(x*log2e + B2)

typedef __attribute__((ext_vector_type(8))) short short8;
typedef __attribute__((ext_vector_type(4))) float f32x4;

__device__ __forceinline__ short f2bf(float x) {
    unsigned u = __builtin_bit_cast(unsigned, x);
    unsigned r = (u + 0x7fffu + ((u >> 16) & 1u)) >> 16;   // RNE
    return (short)r;
}

// ---- prep: fp32 protos [150][128] -> bf16 padded [160][128] in ws ----
__global__ __launch_bounds__(256) void proto_prep(
    const float* __restrict__ protos, unsigned short* __restrict__ dst)
{
    const int tid = threadIdx.x;
#pragma unroll 4
    for (int i = 0; i < (NCP * FD) / 256; ++i) {
        int idx = i * 256 + tid;
        int row = idx >> 7;
        int col = idx & 127;
        float v = (row < NC) ? protos[row * FD + col] : 0.0f;
        dst[idx] = (unsigned short)f2bf(v);
    }
}

// ---- main: persistent, each wave grid-strides over 16-sample tiles ----
__global__ __launch_bounds__(256, 3) void proto_ce_mfma(
    const float*          __restrict__ feats,
    const int*            __restrict__ labels,
    const unsigned short* __restrict__ protos_bf,  // [160][128] bf16 row-major
    double*               __restrict__ partials)
{
    __shared__ __align__(16) char lds[NCP * FD * 2];   // 40 KB, XOR-swizzled protos

    const int tid = threadIdx.x;

    // stage protos global->LDS, st-row swizzle: byte_in_row ^= (row&7)<<4
    {
        const uint4* src = (const uint4*)protos_bf;
#pragma unroll
        for (int i = 0; i < (NCP * FD * 2) / 16 / 256; ++i) {   // 10 iters
            int e8  = i * 256 + tid;
            int row = e8 >> 4;
            int binr = (e8 & 15) << 4;
            int dst = row * 256 + (binr ^ ((row & 7) << 4));
            *(uint4*)(lds + dst) = src[e8];
        }
    }
    __syncthreads();

    const int lane = tid & 63;
    const int wave = tid >> 6;
    const int col  = lane & 15;     // sample within tile / A-row within class tile
    const int grp  = lane >> 4;     // k-group
    const int gw   = blockIdx.x * 4 + wave;

    // swizzled LDS read address decomposition:
    // abyte(tt,kb) = (tt*16+col)*256 + ((kb*64+grp*16) ^ ((col&7)<<4))
    //             = a0 + (kb*64 ^ ahi) + tt*4096   (tt*4096 -> ds offset imm)
    const int sw  = (col & 7) << 4;
    const int a0  = col * 256 + ((grp * 16) ^ (sw & 0x30));
    const int ahi = sw & 0x40;

    const int lrel = -grp * 4;      // match when tt*16+r == lbl - grp*4
    const int vcnt = 6 - grp * 4;   // #valid r in class-tile 9 for this grp

    float4 buf[8];                  // one 16-sample tile slice: 8 x float4 per lane
    const long lane_off = (long)col * (FD / 4) + grp * 2;   // float4 units

    {   // prologue load, tile gw
        const float4* fp = (const float4*)(feats + (long)gw * (16 * FD)) + lane_off;
#pragma unroll
        for (int kb = 0; kb < 4; ++kb) {
            buf[kb * 2]     = fp[kb * 8];
            buf[kb * 2 + 1] = fp[kb * 8 + 1];
        }
    }

    float loss_acc = 0.0f;
    int t = gw;

    while (true) {
        // ---- per-sample L2 norm (fp32, raw floats; matches reference) ----
        float ssq = 0.0f;
#pragma unroll
        for (int i = 0; i < 8; ++i)
            ssq += buf[i].x * buf[i].x + buf[i].y * buf[i].y +
                   buf[i].z * buf[i].z + buf[i].w * buf[i].w;
        ssq += __shfl_xor(ssq, 16, 64);
        ssq += __shfl_xor(ssq, 32, 64);
        const float scl = rsqrtf(fmaxf(ssq, 1e-24f));

        const int lbl = labels[t * 16 + col];      // issued early, used in epilogue

        const int  tn   = t + NWAVE;
        const bool more = (tn < NTILE);
        const float4* fpn = (const float4*)(feats + (long)tn * (16 * FD)) + lane_off;

        f32x4 acc[10];
#pragma unroll
        for (int i = 0; i < 10; ++i) acc[i] = (f32x4){0.f, 0.f, 0.f, 0.f};

        // ---- per k-block: convert (frees 2 buf slots) -> prefetch into them
        //      -> 10x {ds_read + MFMA}. Only ONE short8 fragment live at a time.
#pragma unroll
        for (int kb = 0; kb < 4; ++kb) {
            float4 A = buf[kb * 2], Bv = buf[kb * 2 + 1];
            short8 bfr;
            bfr[0] = f2bf(A.x);  bfr[1] = f2bf(A.y);
            bfr[2] = f2bf(A.z);  bfr[3] = f2bf(A.w);
            bfr[4] = f2bf(Bv.x); bfr[5] = f2bf(Bv.y);
            bfr[6] = f2bf(Bv.z); bfr[7] = f2bf(Bv.w);

            if (more) {                          // prefetch next tile, same slots
                buf[kb * 2]     = fpn[kb * 8];
                buf[kb * 2 + 1] = fpn[kb * 8 + 1];
            }

            const char* ap = lds + (a0 + ((kb * 64) ^ ahi));
#pragma unroll
            for (int tt = 0; tt < 10; ++tt) {
                short8 af = *(const short8*)(ap + tt * 4096);
                acc[tt] = __builtin_amdgcn_mfma_f32_16x16x32_bf16(af, bfr, acc[tt], 0, 0, 0);
            }
        }

        // ---- epilogue: lane holds 40 raw logits (pre-scale) for sample `col` ----
        const float k2 = scl * (INV_T * LOG2E);
        const int   lm = lbl + lrel;            // match when tt*16+r == lm
        float s0 = 0.f, s1 = 0.f, s2 = 0.f, s3 = 0.f;
        float pick = 0.0f;
#pragma unroll
        for (int tt = 0; tt < 10; ++tt) {
#pragma unroll
            for (int r = 0; r < 4; ++r) {
                float a = acc[tt][r];
                float e = exp2f(fmaf(a, k2, B2));
                if (tt < 9) {
                    if      (r == 0) s0 += e;
                    else if (r == 1) s1 += e;
                    else if (r == 2) s2 += e;
                    else             s3 += e;
                } else {
                    s0 += (r < vcnt) ? e : 0.0f;   // mask padded classes 150..159
                }
                pick = (tt * 16 + r == lm) ? a : pick;
            }
        }
        float ssum = (s0 + s1) + (s2 + s3);
        ssum += __shfl_xor(ssum, 16, 64);
        ssum += __shfl_xor(ssum, 32, 64);
        pick += __shfl_xor(pick, 16, 64);
        pick += __shfl_xor(pick, 32, 64);

        loss_acc += __logf(ssum) + MB - pick * (scl * INV_T);

        if (!more) break;
        t = tn;
    }

    // sum the 16 samples (4 grp copies identical; reduce within 16-lane group)
    loss_acc += __shfl_xor(loss_acc, 1, 64);
    loss_acc += __shfl_xor(loss_acc, 2, 64);
    loss_acc += __shfl_xor(loss_acc, 4, 64);
    loss_acc += __shfl_xor(loss_acc, 8, 64);
    if (lane == 0)
        atomicAdd(&partials[gw & 255], (double)loss_acc);
}

__global__ __launch_bounds__(256) void proto_ce_final(
    const double* __restrict__ partials, float* __restrict__ out)
{
    const int tid = threadIdx.x;
    double v = partials[tid];
#pragma unroll
    for (int off = 32; off > 0; off >>= 1)
        v += __shfl_down(v, off, 64);
    __shared__ double w[4];
    if ((tid & 63) == 0) w[tid >> 6] = v;
    __syncthreads();
    if (tid == 0)
        out[0] = (float)((w[0] + w[1] + w[2] + w[3]) * (1.0 / (double)NS));
}

extern "C" void kernel_launch(void* const* d_in, const int* in_sizes, int n_in,
                              void* d_out, int out_size, void* d_ws, size_t ws_size,
                              hipStream_t stream)
{
    const float* feats  = (const float*)d_in[0];
    const int*   labels = (const int*)d_in[1];
    const float* protos = (const float*)d_in[2];

    unsigned short* protos_bf = (unsigned short*)d_ws;                 // 40960 B
    double* partials = (double*)((char*)d_ws + NCP * FD * 2);          // 2048 B

    (void)hipMemsetAsync(partials, 0, 256 * sizeof(double), stream);
    proto_prep<<<1, 256, 0, stream>>>(protos, protos_bf);
    proto_ce_mfma<<<NBLK, 256, 0, stream>>>(feats, labels, protos_bf, partials);
    proto_ce_final<<<1, 256, 0, stream>>>(partials, (float*)d_out);
}

// Round 7
// 188.651 us; speedup vs baseline: 2.7298x; 2.7298x over previous
//
#include <hip/hip_runtime.h>

// proto-contrastive CE loss via bf16 MFMA.
// features [N=1e6, D=128] f32, labels [N] i32, prototypes [C=150, D=128] f32.
// out[0] = mean_n( logsumexp_c(f_hat·p_c/T) - f_hat·p_lbl/T )
//
// R7: persistent blocks (protos staged once) + STATELESS inner loop.
// R4-R6 lesson: any loop-carried prefetch buffer under a launch_bounds cap
// spills (allocator splits VGPR/AGPR evenly; 160 MB scratch traffic). TLP
// covers HBM latency at 16 waves/CU: demand 82 B/cy/CU >> 10 needed. No
// launch_bounds minimum; peak live ~88 regs -> no spill expected.

#define NS 1000000
#define NC 150
#define NCP 160              // classes padded to 10 tiles of 16
#define FD 128
#define NTILE (NS / 16)      // 62500 16-sample tiles
#define NBLK 1024            // persistent blocks, 4 waves each
#define NWAVE (NBLK * 4)     // 4096 waves; 15-16 tiles per wave

static constexpr float INV_T  = 1.0f / 0.15f;
static constexpr float MB     = 1.0f / 0.15f;     // fixed LSE shift, |logit| <= 1/T
static constexpr float LOG2E  = 1.4426950408889634f;
static constexpr float B2     = -MB * LOG2E;      // exp(x-MB) = exp2(x*log2e + B2)

typedef __attribute__((ext_vector_type(8))) short short8;
typedef __attribute__((ext_vector_type(4))) float f32x4;

__device__ __forceinline__ short f2bf(float x) {
    unsigned u = __builtin_bit_cast(unsigned, x);
    unsigned r = (u + 0x7fffu + ((u >> 16) & 1u)) >> 16;   // RNE
    return (short)r;
}

// ---- prep: fp32 protos [150][128] -> bf16 padded [160][128] in ws ----
__global__ __launch_bounds__(256) void proto_prep(
    const float* __restrict__ protos, unsigned short* __restrict__ dst)
{
    const int tid = threadIdx.x;
#pragma unroll 4
    for (int i = 0; i < (NCP * FD) / 256; ++i) {
        int idx = i * 256 + tid;
        int row = idx >> 7;
        int col = idx & 127;
        float v = (row < NC) ? protos[row * FD + col] : 0.0f;
        dst[idx] = (unsigned short)f2bf(v);
    }
}

// ---- main: persistent, stateless per-tile body ----
__global__ __launch_bounds__(256) void proto_ce_mfma(
    const float*          __restrict__ feats,
    const int*            __restrict__ labels,
    const unsigned short* __restrict__ protos_bf,  // [160][128] bf16 row-major
    double*               __restrict__ partials)
{
    __shared__ __align__(16) char lds[NCP * FD * 2];   // 40 KB, XOR-swizzled protos

    const int tid = threadIdx.x;

    // stage protos global->LDS, st-row swizzle: byte_in_row ^= (row&7)<<4
    {
        const uint4* src = (const uint4*)protos_bf;
#pragma unroll
        for (int i = 0; i < (NCP * FD * 2) / 16 / 256; ++i) {   // 10 iters
            int e8  = i * 256 + tid;
            int row = e8 >> 4;
            int binr = (e8 & 15) << 4;
            int dst = row * 256 + (binr ^ ((row & 7) << 4));
            *(uint4*)(lds + dst) = src[e8];
        }
    }
    __syncthreads();

    const int lane = tid & 63;
    const int wave = tid >> 6;
    const int col  = lane & 15;     // sample within tile / A-row within class tile
    const int grp  = lane >> 4;     // k-group
    const int gw   = blockIdx.x * 4 + wave;

    // swizzled LDS read address decomposition:
    // abyte(tt,kb) = (tt*16+col)*256 + ((kb*64+grp*16) ^ ((col&7)<<4))
    //             = a0 + (kb*64 ^ ahi) + tt*4096   (tt*4096 -> ds offset imm)
    const int sw  = (col & 7) << 4;
    const int a0  = col * 256 + ((grp * 16) ^ (sw & 0x30));
    const int ahi = sw & 0x40;

    const int lrel = -grp * 4;      // match when tt*16+r == lbl - grp*4
    const int vcnt = 6 - grp * 4;   // #valid r in class-tile 9 for this grp

    const long lane_off = (long)col * (FD / 4) + grp * 2;   // float4 units

    float loss_acc = 0.0f;

    for (int t = gw; t < NTILE; t += NWAVE) {
        // ---- load this tile's feature slice: 8 x float4 per lane ----
        const float4* fp = (const float4*)(feats + (long)t * (16 * FD)) + lane_off;
        float4 buf[8];
#pragma unroll
        for (int kb = 0; kb < 4; ++kb) {
            buf[kb * 2]     = fp[kb * 8];
            buf[kb * 2 + 1] = fp[kb * 8 + 1];
        }
        const int lbl = labels[t * 16 + col];   // independent, overlaps

        // ---- per-sample L2 norm (fp32; matches reference) ----
        float ssq = 0.0f;
#pragma unroll
        for (int i = 0; i < 8; ++i)
            ssq += buf[i].x * buf[i].x + buf[i].y * buf[i].y +
                   buf[i].z * buf[i].z + buf[i].w * buf[i].w;
        ssq += __shfl_xor(ssq, 16, 64);
        ssq += __shfl_xor(ssq, 32, 64);
        const float scl = rsqrtf(fmaxf(ssq, 1e-24f));

        f32x4 acc[10];
#pragma unroll
        for (int i = 0; i < 10; ++i) acc[i] = (f32x4){0.f, 0.f, 0.f, 0.f};

        // ---- per k-block: convert (buf slots die) -> 10x {ds_read + MFMA} ----
#pragma unroll
        for (int kb = 0; kb < 4; ++kb) {
            float4 A = buf[kb * 2], Bv = buf[kb * 2 + 1];
            short8 bfr;
            bfr[0] = f2bf(A.x);  bfr[1] = f2bf(A.y);
            bfr[2] = f2bf(A.z);  bfr[3] = f2bf(A.w);
            bfr[4] = f2bf(Bv.x); bfr[5] = f2bf(Bv.y);
            bfr[6] = f2bf(Bv.z); bfr[7] = f2bf(Bv.w);

            const char* ap = lds + (a0 + ((kb * 64) ^ ahi));
#pragma unroll
            for (int tt = 0; tt < 10; ++tt) {
                short8 af = *(const short8*)(ap + tt * 4096);
                acc[tt] = __builtin_amdgcn_mfma_f32_16x16x32_bf16(af, bfr, acc[tt], 0, 0, 0);
            }
        }

        // ---- epilogue: lane holds 40 raw logits (pre-scale) for sample `col` ----
        const float k2 = scl * (INV_T * LOG2E);
        const int   lm = lbl + lrel;            // match when tt*16+r == lm
        float s0 = 0.f, s1 = 0.f, s2 = 0.f, s3 = 0.f;
        float pick = 0.0f;
#pragma unroll
        for (int tt = 0; tt < 10; ++tt) {
#pragma unroll
            for (int r = 0; r < 4; ++r) {
                float a = acc[tt][r];
                float e = exp2f(fmaf(a, k2, B2));
                if (tt < 9) {
                    if      (r == 0) s0 += e;
                    else if (r == 1) s1 += e;
                    else if (r == 2) s2 += e;
                    else             s3 += e;
                } else {
                    s0 += (r < vcnt) ? e : 0.0f;   // mask padded classes 150..159
                }
                pick = (tt * 16 + r == lm) ? a : pick;
            }
        }
        float ssum = (s0 + s1) + (s2 + s3);
        ssum += __shfl_xor(ssum, 16, 64);
        ssum += __shfl_xor(ssum, 32, 64);
        pick += __shfl_xor(pick, 16, 64);
        pick += __shfl_xor(pick, 32, 64);

        loss_acc += __logf(ssum) + MB - pick * (scl * INV_T);
    }

    // sum the 16 samples (4 grp copies identical; reduce within 16-lane group)
    loss_acc += __shfl_xor(loss_acc, 1, 64);
    loss_acc += __shfl_xor(loss_acc, 2, 64);
    loss_acc += __shfl_xor(loss_acc, 4, 64);
    loss_acc += __shfl_xor(loss_acc, 8, 64);
    if (lane == 0)
        atomicAdd(&partials[gw & 255], (double)loss_acc);
}

__global__ __launch_bounds__(256) void proto_ce_final(
    const double* __restrict__ partials, float* __restrict__ out)
{
    const int tid = threadIdx.x;
    double v = partials[tid];
#pragma unroll
    for (int off = 32; off > 0; off >>= 1)
        v += __shfl_down(v, off, 64);
    __shared__ double w[4];
    if ((tid & 63) == 0) w[tid >> 6] = v;
    __syncthreads();
    if (tid == 0)
        out[0] = (float)((w[0] + w[1] + w[2] + w[3]) * (1.0 / (double)NS));
}

extern "C" void kernel_launch(void* const* d_in, const int* in_sizes, int n_in,
                              void* d_out, int out_size, void* d_ws, size_t ws_size,
                              hipStream_t stream)
{
    const float* feats  = (const float*)d_in[0];
    const int*   labels = (const int*)d_in[1];
    const float* protos = (const float*)d_in[2];

    unsigned short* protos_bf = (unsigned short*)d_ws;                 // 40960 B
    double* partials = (double*)((char*)d_ws + NCP * FD * 2);          // 2048 B

    (void)hipMemsetAsync(partials, 0, 256 * sizeof(double), stream);
    proto_prep<<<1, 256, 0, stream>>>(protos, protos_bf);
    proto_ce_mfma<<<NBLK, 256, 0, stream>>>(feats, labels, protos_bf, partials);
    proto_ce_final<<<1, 256, 0, stream>>>(partials, (float*)d_out);
}